// Round 9
// baseline (288.195 us; speedup 1.0000x reference)
//
#include <hip/hip_runtime.h>
#include <hip/hip_bf16.h>
#include <math.h>

#define D_MODEL 1024
#define N_HEADS 16
#define HEAD_DIM 64
#define SEQ1 1536
#define SEQ2 512
#define NTOT 2048
#define BATCH 2

typedef __attribute__((ext_vector_type(8))) short bf16x8;    // 8 bf16 = 4 VGPR
typedef __attribute__((ext_vector_type(4))) float f32x4;
typedef __attribute__((ext_vector_type(16))) float f32x16;

__device__ __forceinline__ unsigned short f2bf(float f) {
  unsigned u = __builtin_bit_cast(unsigned, f);
  u += 0x7FFFu + ((u >> 16) & 1u);          // RNE
  return (unsigned short)(u >> 16);
}
__device__ __forceinline__ float bf2f(unsigned short h) {
  unsigned u = ((unsigned)h) << 16;
  return __builtin_bit_cast(float, u);
}
__device__ __forceinline__ unsigned packbf(float a, float b) {
  return (unsigned)f2bf(a) | ((unsigned)f2bf(b) << 16);
}

// async global->LDS, 16B per lane. dst wave-uniform; HW writes dst + lane*16.
__device__ __forceinline__ void gload16(const void* g, void* l) {
  __builtin_amdgcn_global_load_lds(
      (const __attribute__((address_space(1))) void*)g,
      (__attribute__((address_space(3))) void*)l, 16, 0, 0);
}

// ---------------------------------------------------------------------------
// Single fused fp32 -> bf16 conversion over 6 segments.
// ---------------------------------------------------------------------------
struct CvtArgs {
  const float* src[6];
  unsigned short* dst[6];
  int prefix[7];
};

__global__ __launch_bounds__(256) void cvt_all(CvtArgs a)
{
  int e = (blockIdx.x * 256 + threadIdx.x) * 4;
  if (e >= a.prefix[6]) return;
  int s = 0;
#pragma unroll
  for (int i = 1; i < 6; ++i) s += (e >= a.prefix[i]) ? 1 : 0;
  int lo = e - a.prefix[s];
  float4 v = *(const float4*)(a.src[s] + lo);
  ushort4 o;
  o.x = f2bf(v.x); o.y = f2bf(v.y); o.z = f2bf(v.z); o.w = f2bf(v.w);
  *(ushort4*)(a.dst[s] + lo) = o;
}

// ---------------------------------------------------------------------------
// Batched bf16 MFMA GEMM over 2 segments: C = A @ W^T + bias.
// 128x128 tile, BK=64, 4 waves; m97 structure (gload_lds w=16, swizzled src).
// ---------------------------------------------------------------------------
struct GemmSeg {
  const unsigned short* A;
  const unsigned short* W;
  const float* bias;
  void* C;
  int N, K, tilesX;
};

template <int WRITE_BF16>
__global__ __launch_bounds__(256) void gemm2(GemmSeg g0, GemmSeg g1, int tiles0)
{
  __shared__ __align__(16) unsigned short Alds[128 * 64];   // 16 KB
  __shared__ __align__(16) unsigned short Blds[128 * 64];
  const int id = blockIdx.x;
  const bool in1 = (id >= tiles0);
  const unsigned short* A = in1 ? g1.A : g0.A;
  const unsigned short* W = in1 ? g1.W : g0.W;
  const float* bias = in1 ? g1.bias : g0.bias;
  void* Cv = in1 ? g1.C : g0.C;
  const int N = in1 ? g1.N : g0.N;
  const int K = in1 ? g1.K : g0.K;
  const int tilesX = in1 ? g1.tilesX : g0.tilesX;
  const int lid = in1 ? id - tiles0 : id;
  const int m0 = (lid / tilesX) * 128, n0 = (lid % tilesX) * 128;

  const int tid = threadIdx.x;
  const int lane = tid & 63, wave = tid >> 6;
  const int wm = wave >> 1, wn = wave & 1;
  const int l15 = lane & 15, l4 = lane >> 4;

  f32x4 acc[4][4];
#pragma unroll
  for (int m = 0; m < 4; ++m)
#pragma unroll
    for (int n = 0; n < 4; ++n)
#pragma unroll
      for (int r = 0; r < 4; ++r) acc[m][n][r] = 0.0f;

  for (int k0 = 0; k0 < K; k0 += 64) {
    __syncthreads();
#pragma unroll
    for (int c = 0; c < 4; ++c) {
      int off = c * 4096 + tid * 16;
      int row = off >> 7;
      int c16g = ((off & 127) >> 4) ^ (row & 7);
      int dstb = c * 4096 + (tid >> 6) * 1024;
      gload16(A + (size_t)(m0 + row) * K + k0 + c16g * 8, (char*)Alds + dstb);
      gload16(W + (size_t)(n0 + row) * K + k0 + c16g * 8, (char*)Blds + dstb);
    }
    __syncthreads();
#pragma unroll
    for (int kk = 0; kk < 2; ++kk) {
      bf16x8 af[4], bfr[4];
#pragma unroll
      for (int m = 0; m < 4; ++m) {
        int r = wm * 64 + m * 16 + l15;
        int colb = (kk * 64 + l4 * 16) ^ ((r & 7) << 4);
        af[m] = *(const bf16x8*)((const char*)Alds + r * 128 + colb);
      }
#pragma unroll
      for (int n = 0; n < 4; ++n) {
        int r = wn * 64 + n * 16 + l15;
        int colb = (kk * 64 + l4 * 16) ^ ((r & 7) << 4);
        bfr[n] = *(const bf16x8*)((const char*)Blds + r * 128 + colb);
      }
#pragma unroll
      for (int m = 0; m < 4; ++m)
#pragma unroll
        for (int n = 0; n < 4; ++n)
          acc[m][n] = __builtin_amdgcn_mfma_f32_16x16x32_bf16(
              af[m], bfr[n], acc[m][n], 0, 0, 0);
    }
  }

#pragma unroll
  for (int m = 0; m < 4; ++m)
#pragma unroll
    for (int n = 0; n < 4; ++n)
#pragma unroll
      for (int r = 0; r < 4; ++r) {
        int row = m0 + wm * 64 + m * 16 + l4 * 4 + r;
        int col = n0 + wn * 64 + n * 16 + l15;
        float v = acc[m][n][r] + bias[col];
        if (WRITE_BF16)
          ((unsigned short*)Cv)[(size_t)row * N + col] = f2bf(v);
        else
          ((float*)Cv)[(size_t)row * N + col] = v;
      }
}

// ---------------------------------------------------------------------------
// RMSNorm + RoPE on bf16 qkv; q pre-scaled by 0.125*log2(e).
// ---------------------------------------------------------------------------
__global__ __launch_bounds__(256) void qkv_transform(
    const unsigned short* __restrict__ qkv1,
    const unsigned short* __restrict__ qkv2,
    const float* __restrict__ qs1, const float* __restrict__ ks1,
    const float* __restrict__ qs2, const float* __restrict__ ks2,
    unsigned short* __restrict__ qO, unsigned short* __restrict__ kO,
    unsigned short* __restrict__ vO)
{
  const int row = blockIdx.x;
  const int lane = threadIdx.x & 63;
  const int wave = threadIdx.x >> 6;
  const float QSCALE = 0.18033688011112042f;  // 0.125 * log2(e)

  const unsigned short* src;
  const float* qs;
  const float* ks;
  int b, pos;
  if (row < BATCH * SEQ1) {
    b = row / SEQ1;
    pos = row % SEQ1;
    src = qkv1 + (size_t)row * (3 * D_MODEL);
    qs = qs1; ks = ks1;
  } else {
    int r2 = row - BATCH * SEQ1;
    b = r2 / SEQ2;
    pos = SEQ1 + (r2 % SEQ2);
    src = qkv2 + (size_t)r2 * (3 * D_MODEL);
    qs = qs2; ks = ks2;
  }

  const int j = lane >> 1;
  const float LOG2_THETA = 13.287712379549449f;
  float inv_freq = exp2f(-((float)(2 * j) / 64.0f) * LOG2_THETA);
  float ang = (float)pos * inv_freq;
  float sn, cs;
  sincosf(ang, &sn, &cs);

  for (int h = wave; h < N_HEADS; h += 4) {
    float xq = bf2f(src[0 * D_MODEL + h * HEAD_DIM + lane]);
    float xk = bf2f(src[1 * D_MODEL + h * HEAD_DIM + lane]);
    float xv = bf2f(src[2 * D_MODEL + h * HEAD_DIM + lane]);

    float sq = xq * xq, sk = xk * xk;
#pragma unroll
    for (int o = 32; o > 0; o >>= 1) {
      sq += __shfl_xor(sq, o);
      sk += __shfl_xor(sk, o);
    }
    float xqn = xq * rsqrtf(sq * (1.0f / 64.0f) + 1e-6f) * qs[lane];
    float xkn = xk * rsqrtf(sk * (1.0f / 64.0f) + 1e-6f) * ks[lane];

    float pq = __shfl_xor(xqn, 1);
    float pk = __shfl_xor(xkn, 1);
    float oq, ok;
    if (lane & 1) { oq = pq * sn + xqn * cs; ok = pk * sn + xkn * cs; }
    else          { oq = xqn * cs - pq * sn; ok = xkn * cs - pk * sn; }

    size_t o = (((size_t)b * N_HEADS + h) * NTOT + pos) * HEAD_DIM + lane;
    qO[o] = f2bf(oq * QSCALE);
    kO[o] = f2bf(ok);
    vO[o] = f2bf(xv);
  }
}

// ---------------------------------------------------------------------------
// V transpose: (BH, NTOT, 64) -> (BH, 64, NTOT), bf16, 64x64 tiles.
// ---------------------------------------------------------------------------
__global__ __launch_bounds__(256) void v_transpose(
    const unsigned short* __restrict__ v, unsigned short* __restrict__ vt)
{
  const int pt = blockIdx.x, bh = blockIdx.y;
  __shared__ unsigned short t[64][72];
  const int tid = threadIdx.x;
  const unsigned short* src = v + ((size_t)bh * NTOT + pt * 64) * 64;
#pragma unroll
  for (int c = 0; c < 2; ++c) {
    int off = c * 4096 + tid * 16;
    int row = off >> 7, c16 = (off & 127) >> 4;
    bf16x8 x = *(const bf16x8*)(src + row * 64 + c16 * 8);
#pragma unroll
    for (int j = 0; j < 8; ++j) t[row][c16 * 8 + j] = (unsigned short)x[j];
  }
  __syncthreads();
  unsigned short* dst = vt + (size_t)bh * 64 * NTOT + pt * 64;
#pragma unroll
  for (int c = 0; c < 2; ++c) {
    int off = c * 4096 + tid * 16;
    int d = off >> 7, p16 = (off & 127) >> 4;
    bf16x8 x;
#pragma unroll
    for (int j = 0; j < 8; ++j) x[j] = (short)t[p16 * 8 + j][d];
    *(bf16x8*)(dst + (size_t)d * NTOT + p16 * 8) = x;
  }
}

// ---------------------------------------------------------------------------
// MFMA flash attention, 32x32 fragments, fully in-register P (no P LDS).
// QBLK=128, 4 waves x 32 q-rows. S^T = mfma_32x32(K, Q): col(lane&31)=q ->
// m/l/rescale/normalize are lane-local scalars. P packed to bf16 pairs in
// regs; PV B-fragments assembled via 4x shfl_xor(32) + cndmask per k-tile.
// O^T = mfma_32x32(V^T, P) accumulates with the same per-lane-q alignment.
// K/V dbuf + single barrier + setprio kept (verified r6-r8).
// ---------------------------------------------------------------------------
__global__ __launch_bounds__(256) void attn_mfma(
    const unsigned short* __restrict__ Qg, const unsigned short* __restrict__ Kg,
    const unsigned short* __restrict__ VTg,
    unsigned short* __restrict__ xb1, unsigned short* __restrict__ xb2)
{
  const int qt = blockIdx.x, bh = blockIdx.y;
  const int b = bh >> 4, head = bh & 15;
  const int tid = threadIdx.x, lane = tid & 63, w = tid >> 6;
  const int ql = lane & 31, hf = lane >> 5;

  __shared__ __align__(16) unsigned short Klds[2][64 * 64];   // 2 x 8 KB
  __shared__ __align__(16) unsigned short Vlds[2][64 * 64];   // 2 x 8 KB (V^T)

  const size_t base = (size_t)bh * NTOT * HEAD_DIM;

  // Q B-fragments: lane holds q = block q-row (w*32 + ql), d = s*16 + hf*8 ..+7
  bf16x8 qf[4];
  {
    const unsigned short* qp =
        Qg + base + (size_t)(qt * 128 + w * 32 + ql) * 64 + hf * 8;
#pragma unroll
    for (int s = 0; s < 4; ++s) qf[s] = *(const bf16x8*)(qp + s * 16);
  }

  f32x16 acc_o[2];
#pragma unroll
  for (int dt = 0; dt < 2; ++dt)
#pragma unroll
    for (int r = 0; r < 16; ++r) acc_o[dt][r] = 0.0f;
  float m_run = -1e30f, l_run = 0.0f;

  const unsigned short* kp = Kg + base;
  const unsigned short* vtp = VTg + (size_t)bh * HEAD_DIM * NTOT;

#define STAGE(bf, kt)                                                         \
  {                                                                           \
    _Pragma("unroll")                                                         \
    for (int c = 0; c < 2; ++c) {                                             \
      int off = c * 4096 + tid * 16;                                          \
      int row = off >> 7;                                                     \
      int c16g = ((off & 127) >> 4) ^ (row & 7);                              \
      int dstb = c * 4096 + (tid >> 6) * 1024;                                \
      gload16(kp + (size_t)((kt) * 64 + row) * 64 + c16g * 8,                 \
              (char*)Klds[bf] + dstb);                                        \
      gload16(vtp + (size_t)row * NTOT + (kt) * 64 + c16g * 8,                \
              (char*)Vlds[bf] + dstb);                                        \
    }                                                                         \
  }

  STAGE(0, 0);

  for (int kt = 0; kt < NTOT / 64; ++kt) {
    const int cur = kt & 1;
    __syncthreads();   // rendezvous + vmcnt drain: buf[cur] staged,
                       // all waves done reading buf[cur^1]
    if (kt + 1 < NTOT / 64) STAGE(cur ^ 1, kt + 1);

    // S^T[t]: D[k32][q32], col = ql = q, row k = (r&3) + 8*(r>>2) + 4*hf
    f32x16 sacc[2];
#pragma unroll
    for (int t = 0; t < 2; ++t)
#pragma unroll
      for (int r = 0; r < 16; ++r) sacc[t][r] = 0.0f;
    __builtin_amdgcn_s_setprio(1);
#pragma unroll
    for (int t = 0; t < 2; ++t) {
#pragma unroll
      for (int s = 0; s < 4; ++s) {           // d contraction steps
        int row = t * 32 + ql;
        int colb = (s * 32 + hf * 16) ^ ((row & 7) << 4);
        bf16x8 kf = *(const bf16x8*)((const char*)Klds[cur] + row * 128 + colb);
        sacc[t] = __builtin_amdgcn_mfma_f32_32x32x16_bf16(
            kf, qf[s], sacc[t], 0, 0, 0);
      }
    }
    __builtin_amdgcn_s_setprio(0);

    // ---- softmax, fully lane-local (lane owns q = ql; halves split k) ----
    float tm = sacc[0][0];
#pragma unroll
    for (int t = 0; t < 2; ++t)
#pragma unroll
      for (int r = 0; r < 16; ++r) tm = fmaxf(tm, sacc[t][r]);
    tm = fmaxf(tm, __shfl_xor(tm, 32));
    if (!__all(tm <= m_run + 8.0f)) {        // defer-max (THR=8, exp2 dom)
      float mn = fmaxf(m_run, tm);
      float fac = exp2f(m_run - mn);
      m_run = mn;
      l_run *= fac;
#pragma unroll
      for (int dt = 0; dt < 2; ++dt)
#pragma unroll
        for (int r = 0; r < 16; ++r) acc_o[dt][r] *= fac;
    }
    const float mc = m_run;

    // p = exp2(S - m); pack bf16 pairs c[t][2a+b] = (k=8a+4hf+2b, +1)
    unsigned c0[8], c1[8];
    float rs = 0.0f;
    {
      float p0[16], p1[16];
#pragma unroll
      for (int r = 0; r < 16; ++r) {
        p0[r] = exp2f(sacc[0][r] - mc);
        p1[r] = exp2f(sacc[1][r] - mc);
        rs += p0[r] + p1[r];
      }
#pragma unroll
      for (int a = 0; a < 4; ++a) {
        c0[2 * a + 0] = packbf(p0[4 * a + 0], p0[4 * a + 1]);
        c0[2 * a + 1] = packbf(p0[4 * a + 2], p0[4 * a + 3]);
        c1[2 * a + 0] = packbf(p1[4 * a + 0], p1[4 * a + 1]);
        c1[2 * a + 1] = packbf(p1[4 * a + 2], p1[4 * a + 3]);
      }
    }
    rs += __shfl_xor(rs, 32);
    l_run += rs;

    // half-exchange: partner pairs via shfl_xor(32)
    unsigned r0[4], r1[4];
    r0[0] = __shfl_xor(hf ? c0[0] : c0[2], 32);
    r0[1] = __shfl_xor(hf ? c0[1] : c0[3], 32);
    r0[2] = __shfl_xor(hf ? c0[4] : c0[6], 32);
    r0[3] = __shfl_xor(hf ? c0[5] : c0[7], 32);
    r1[0] = __shfl_xor(hf ? c1[0] : c1[2], 32);
    r1[1] = __shfl_xor(hf ? c1[1] : c1[3], 32);
    r1[2] = __shfl_xor(hf ? c1[4] : c1[6], 32);
    r1[3] = __shfl_xor(hf ? c1[5] : c1[7], 32);

    // ---- PV: O^T[dt] += V^T-frag x P-frag over 4 k-steps ----
    __builtin_amdgcn_s_setprio(1);
#pragma unroll
    for (int s = 0; s < 4; ++s) {
      uint4 pw;
      const unsigned* cc = (s < 2) ? c0 : c1;
      const unsigned* rr = (s < 2) ? r0 : r1;
      if ((s & 1) == 0) {
        pw.x = hf ? rr[0] : cc[0];
        pw.y = hf ? rr[1] : cc[1];
        pw.z = hf ? cc[2] : rr[0];
        pw.w = hf ? cc[3] : rr[1];
      } else {
        pw.x = hf ? rr[2] : cc[4];
        pw.y = hf ? rr[3] : cc[5];
        pw.z = hf ? cc[6] : rr[2];
        pw.w = hf ? cc[7] : rr[3];
      }
      bf16x8 pfrag = __builtin_bit_cast(bf16x8, pw);
#pragma unroll
      for (int dt = 0; dt < 2; ++dt) {
        int row = dt * 32 + ql;
        int colb = (s * 32 + hf * 16) ^ ((row & 7) << 4);
        bf16x8 vf = *(const bf16x8*)((const char*)Vlds[cur] + row * 128 + colb);
        acc_o[dt] = __builtin_amdgcn_mfma_f32_32x32x16_bf16(
            vf, pfrag, acc_o[dt], 0, 0, 0);
      }
    }
    __builtin_amdgcn_s_setprio(0);
  }
#undef STAGE

  // epilogue: lane owns q = ql; d = dt*32 + 8*rq + 4*hf + b
  {
    float inv = 1.0f / l_run;
    int n = qt * 128 + w * 32 + ql;
    unsigned short* dst;
    if (n < SEQ1) dst = xb1 + ((size_t)b * SEQ1 + n) * D_MODEL;
    else          dst = xb2 + ((size_t)b * SEQ2 + (n - SEQ1)) * D_MODEL;
#pragma unroll
    for (int dt = 0; dt < 2; ++dt)
#pragma unroll
      for (int rq = 0; rq < 4; ++rq) {
        ushort4 o;
        o.x = f2bf(acc_o[dt][rq * 4 + 0] * inv);
        o.y = f2bf(acc_o[dt][rq * 4 + 1] * inv);
        o.z = f2bf(acc_o[dt][rq * 4 + 2] * inv);
        o.w = f2bf(acc_o[dt][rq * 4 + 3] * inv);
        *(ushort4*)(dst + head * 64 + dt * 32 + rq * 8 + hf * 4) = o;
      }
  }
}

// ---------------------------------------------------------------------------
extern "C" void kernel_launch(void* const* d_in, const int* in_sizes, int n_in,
                              void* d_out, int out_size, void* d_ws,
                              size_t ws_size, hipStream_t stream)
{
  (void)in_sizes; (void)n_in; (void)out_size; (void)ws_size;

  const float* x1  = (const float*)d_in[0];
  const float* x2  = (const float*)d_in[1];
  const float* Wq1 = (const float*)d_in[2];
  const float* bq1 = (const float*)d_in[3];
  const float* Wq2 = (const float*)d_in[4];
  const float* bq2 = (const float*)d_in[5];
  const float* Wo1 = (const float*)d_in[6];
  const float* bo1 = (const float*)d_in[7];
  const float* Wo2 = (const float*)d_in[8];
  const float* bo2 = (const float*)d_in[9];
  const float* qs1 = (const float*)d_in[10];
  const float* ks1 = (const float*)d_in[11];
  const float* qs2 = (const float*)d_in[12];
  const float* ks2 = (const float*)d_in[13];
  float* out = (float*)d_out;

  unsigned short* ws = (unsigned short*)d_ws;
  const size_t SX1 = (size_t)BATCH * SEQ1 * D_MODEL;
  const size_t SX2 = (size_t)BATCH * SEQ2 * D_MODEL;
  const size_t SW  = (size_t)3 * D_MODEL * D_MODEL;
  const size_t SWO = (size_t)D_MODEL * D_MODEL;
  const size_t SQ1 = (size_t)BATCH * SEQ1 * 3 * D_MODEL;
  const size_t SQ2 = (size_t)BATCH * SEQ2 * 3 * D_MODEL;
  const size_t SH  = (size_t)BATCH * N_HEADS * NTOT * HEAD_DIM;

  unsigned short* x1b  = ws;
  unsigned short* x2b  = x1b + SX1;
  unsigned short* Wq1b = x2b + SX2;
  unsigned short* Wq2b = Wq1b + SW;
  unsigned short* Wo1b = Wq2b + SW;
  unsigned short* Wo2b = Wo1b + SWO;
  unsigned short* qkv1 = Wo2b + SWO;
  unsigned short* qkv2 = qkv1 + SQ1;
  unsigned short* qb   = qkv2 + SQ2;
  unsigned short* kb   = qb + SH;
  unsigned short* vb   = kb + SH;
  unsigned short* vtb  = vb + SH;
  unsigned short* xb1  = vtb + SH;          // (B,SEQ1,1024) bf16
  unsigned short* xb2  = xb1 + SX1;         // (B,SEQ2,1024) bf16

  // fused fp32 -> bf16 conversion
  CvtArgs ca;
  ca.src[0] = x1;  ca.dst[0] = x1b;
  ca.src[1] = x2;  ca.dst[1] = x2b;
  ca.src[2] = Wq1; ca.dst[2] = Wq1b;
  ca.src[3] = Wq2; ca.dst[3] = Wq2b;
  ca.src[4] = Wo1; ca.dst[4] = Wo1b;
  ca.src[5] = Wo2; ca.dst[5] = Wo2b;
  ca.prefix[0] = 0;
  ca.prefix[1] = (int)SX1;
  ca.prefix[2] = (int)(SX1 + SX2);
  ca.prefix[3] = (int)(SX1 + SX2 + SW);
  ca.prefix[4] = (int)(SX1 + SX2 + 2 * SW);
  ca.prefix[5] = (int)(SX1 + SX2 + 2 * SW + SWO);
  ca.prefix[6] = (int)(SX1 + SX2 + 2 * SW + 2 * SWO);
  cvt_all<<<(ca.prefix[6] / 4 + 255) / 256, 256, 0, stream>>>(ca);

  // QKV projections: one batched dispatch (bf16 out)
  {
    GemmSeg s0{x1b, Wq1b, bq1, qkv1, 3 * D_MODEL, D_MODEL, 3 * D_MODEL / 128};
    GemmSeg s1{x2b, Wq2b, bq2, qkv2, 3 * D_MODEL, D_MODEL, 3 * D_MODEL / 128};
    int t0 = (BATCH * SEQ1 / 128) * (3 * D_MODEL / 128);   // 576
    int t1 = (BATCH * SEQ2 / 128) * (3 * D_MODEL / 128);   // 192
    gemm2<1><<<t0 + t1, 256, 0, stream>>>(s0, s1, t0);
  }

  // RMSNorm + RoPE + scatter
  qkv_transform<<<BATCH * (SEQ1 + SEQ2), 256, 0, stream>>>(
      qkv1, qkv2, qs1, ks1, qs2, ks2, qb, kb, vb);

  // V transpose for PV operand
  v_transpose<<<dim3(NTOT / 64, BATCH * N_HEADS), 256, 0, stream>>>(vb, vtb);

  // attention (QBLK=128, 4 waves x 32q, 32x32 MFMA, in-register P)
  attn_mfma<<<dim3(NTOT / 128, BATCH * N_HEADS), 256, 0, stream>>>(
      qb, kb, vtb, xb1, xb2);

  // output projections: one batched dispatch (f32 out)
  {
    GemmSeg s0{xb1, Wo1b, bo1, out, D_MODEL, D_MODEL, D_MODEL / 128};
    GemmSeg s1{xb2, Wo2b, bo2, out + (size_t)BATCH * SEQ1 * D_MODEL,
               D_MODEL, D_MODEL, D_MODEL / 128};
    int t0 = (BATCH * SEQ1 / 128) * (D_MODEL / 128);   // 192
    int t1 = (BATCH * SEQ2 / 128) * (D_MODEL / 128);   // 64
    gemm2<0><<<t0 + t1, 256, 0, stream>>>(s0, s1, t0);
  }
}

// Round 11
// 272.219 us; speedup vs baseline: 1.0587x; 1.0587x over previous
//
#include <hip/hip_runtime.h>
#include <hip/hip_bf16.h>
#include <math.h>

#define D_MODEL 1024
#define N_HEADS 16
#define HEAD_DIM 64
#define SEQ1 1536
#define SEQ2 512
#define NTOT 2048
#define BATCH 2

typedef __attribute__((ext_vector_type(8))) short bf16x8;    // 8 bf16 = 4 VGPR
typedef __attribute__((ext_vector_type(4))) float f32x4;
typedef __attribute__((ext_vector_type(16))) float f32x16;

__device__ __forceinline__ unsigned short f2bf(float f) {
  unsigned u = __builtin_bit_cast(unsigned, f);
  u += 0x7FFFu + ((u >> 16) & 1u);          // RNE
  return (unsigned short)(u >> 16);
}
__device__ __forceinline__ float bf2f(unsigned short h) {
  unsigned u = ((unsigned)h) << 16;
  return __builtin_bit_cast(float, u);
}
// pack two f32 -> {bf16(a) lo, bf16(b) hi}, truncation rounding, 1 VALU op.
// v_perm_b32: combined bytes 0-3 = src1, 4-7 = src0; sel picks per dest byte.
__device__ __forceinline__ unsigned packbf_rtz(float a, float b) {
  return __builtin_amdgcn_perm(__builtin_bit_cast(unsigned, b),
                               __builtin_bit_cast(unsigned, a), 0x07060302u);
}

// async global->LDS, 16B per lane. dst wave-uniform; HW writes dst + lane*16.
__device__ __forceinline__ void gload16(const void* g, void* l) {
  __builtin_amdgcn_global_load_lds(
      (const __attribute__((address_space(1))) void*)g,
      (__attribute__((address_space(3))) void*)l, 16, 0, 0);
}

// ---------------------------------------------------------------------------
// Single fused fp32 -> bf16 conversion over 6 segments.
// ---------------------------------------------------------------------------
struct CvtArgs {
  const float* src[6];
  unsigned short* dst[6];
  int prefix[7];
};

__global__ __launch_bounds__(256) void cvt_all(CvtArgs a)
{
  int e = (blockIdx.x * 256 + threadIdx.x) * 4;
  if (e >= a.prefix[6]) return;
  int s = 0;
#pragma unroll
  for (int i = 1; i < 6; ++i) s += (e >= a.prefix[i]) ? 1 : 0;
  int lo = e - a.prefix[s];
  float4 v = *(const float4*)(a.src[s] + lo);
  ushort4 o;
  o.x = f2bf(v.x); o.y = f2bf(v.y); o.z = f2bf(v.z); o.w = f2bf(v.w);
  *(ushort4*)(a.dst[s] + lo) = o;
}

// ---------------------------------------------------------------------------
// Batched bf16 MFMA GEMM over 2 segments: C = A @ W^T + bias.
// 128x128 tile, BK=64, 4 waves; m97 structure (gload_lds w=16, swizzled src).
// ---------------------------------------------------------------------------
struct GemmSeg {
  const unsigned short* A;
  const unsigned short* W;
  const float* bias;
  void* C;
  int N, K, tilesX;
};

template <int WRITE_BF16>
__global__ __launch_bounds__(256) void gemm2(GemmSeg g0, GemmSeg g1, int tiles0)
{
  __shared__ __align__(16) unsigned short Alds[128 * 64];   // 16 KB
  __shared__ __align__(16) unsigned short Blds[128 * 64];
  const int id = blockIdx.x;
  const bool in1 = (id >= tiles0);
  const unsigned short* A = in1 ? g1.A : g0.A;
  const unsigned short* W = in1 ? g1.W : g0.W;
  const float* bias = in1 ? g1.bias : g0.bias;
  void* Cv = in1 ? g1.C : g0.C;
  const int N = in1 ? g1.N : g0.N;
  const int K = in1 ? g1.K : g0.K;
  const int tilesX = in1 ? g1.tilesX : g0.tilesX;
  const int lid = in1 ? id - tiles0 : id;
  const int m0 = (lid / tilesX) * 128, n0 = (lid % tilesX) * 128;

  const int tid = threadIdx.x;
  const int lane = tid & 63, wave = tid >> 6;
  const int wm = wave >> 1, wn = wave & 1;
  const int l15 = lane & 15, l4 = lane >> 4;

  f32x4 acc[4][4];
#pragma unroll
  for (int m = 0; m < 4; ++m)
#pragma unroll
    for (int n = 0; n < 4; ++n)
#pragma unroll
      for (int r = 0; r < 4; ++r) acc[m][n][r] = 0.0f;

  for (int k0 = 0; k0 < K; k0 += 64) {
    __syncthreads();
#pragma unroll
    for (int c = 0; c < 4; ++c) {
      int off = c * 4096 + tid * 16;
      int row = off >> 7;
      int c16g = ((off & 127) >> 4) ^ (row & 7);
      int dstb = c * 4096 + (tid >> 6) * 1024;
      gload16(A + (size_t)(m0 + row) * K + k0 + c16g * 8, (char*)Alds + dstb);
      gload16(W + (size_t)(n0 + row) * K + k0 + c16g * 8, (char*)Blds + dstb);
    }
    __syncthreads();
#pragma unroll
    for (int kk = 0; kk < 2; ++kk) {
      bf16x8 af[4], bfr[4];
#pragma unroll
      for (int m = 0; m < 4; ++m) {
        int r = wm * 64 + m * 16 + l15;
        int colb = (kk * 64 + l4 * 16) ^ ((r & 7) << 4);
        af[m] = *(const bf16x8*)((const char*)Alds + r * 128 + colb);
      }
#pragma unroll
      for (int n = 0; n < 4; ++n) {
        int r = wn * 64 + n * 16 + l15;
        int colb = (kk * 64 + l4 * 16) ^ ((r & 7) << 4);
        bfr[n] = *(const bf16x8*)((const char*)Blds + r * 128 + colb);
      }
#pragma unroll
      for (int m = 0; m < 4; ++m)
#pragma unroll
        for (int n = 0; n < 4; ++n)
          acc[m][n] = __builtin_amdgcn_mfma_f32_16x16x32_bf16(
              af[m], bfr[n], acc[m][n], 0, 0, 0);
    }
  }

#pragma unroll
  for (int m = 0; m < 4; ++m)
#pragma unroll
    for (int n = 0; n < 4; ++n)
#pragma unroll
      for (int r = 0; r < 4; ++r) {
        int row = m0 + wm * 64 + m * 16 + l4 * 4 + r;
        int col = n0 + wn * 64 + n * 16 + l15;
        float v = acc[m][n][r] + bias[col];
        if (WRITE_BF16)
          ((unsigned short*)Cv)[(size_t)row * N + col] = f2bf(v);
        else
          ((float*)Cv)[(size_t)row * N + col] = v;
      }
}

// ---------------------------------------------------------------------------
// RMSNorm + RoPE on bf16 qkv; q pre-scaled by 0.125*log2(e).
// ---------------------------------------------------------------------------
__global__ __launch_bounds__(256) void qkv_transform(
    const unsigned short* __restrict__ qkv1,
    const unsigned short* __restrict__ qkv2,
    const float* __restrict__ qs1, const float* __restrict__ ks1,
    const float* __restrict__ qs2, const float* __restrict__ ks2,
    unsigned short* __restrict__ qO, unsigned short* __restrict__ kO,
    unsigned short* __restrict__ vO)
{
  const int row = blockIdx.x;
  const int lane = threadIdx.x & 63;
  const int wave = threadIdx.x >> 6;
  const float QSCALE = 0.18033688011112042f;  // 0.125 * log2(e)

  const unsigned short* src;
  const float* qs;
  const float* ks;
  int b, pos;
  if (row < BATCH * SEQ1) {
    b = row / SEQ1;
    pos = row % SEQ1;
    src = qkv1 + (size_t)row * (3 * D_MODEL);
    qs = qs1; ks = ks1;
  } else {
    int r2 = row - BATCH * SEQ1;
    b = r2 / SEQ2;
    pos = SEQ1 + (r2 % SEQ2);
    src = qkv2 + (size_t)r2 * (3 * D_MODEL);
    qs = qs2; ks = ks2;
  }

  const int j = lane >> 1;
  const float LOG2_THETA = 13.287712379549449f;
  float inv_freq = exp2f(-((float)(2 * j) / 64.0f) * LOG2_THETA);
  float ang = (float)pos * inv_freq;
  float sn, cs;
  sincosf(ang, &sn, &cs);

  for (int h = wave; h < N_HEADS; h += 4) {
    float xq = bf2f(src[0 * D_MODEL + h * HEAD_DIM + lane]);
    float xk = bf2f(src[1 * D_MODEL + h * HEAD_DIM + lane]);
    float xv = bf2f(src[2 * D_MODEL + h * HEAD_DIM + lane]);

    float sq = xq * xq, sk = xk * xk;
#pragma unroll
    for (int o = 32; o > 0; o >>= 1) {
      sq += __shfl_xor(sq, o);
      sk += __shfl_xor(sk, o);
    }
    float xqn = xq * rsqrtf(sq * (1.0f / 64.0f) + 1e-6f) * qs[lane];
    float xkn = xk * rsqrtf(sk * (1.0f / 64.0f) + 1e-6f) * ks[lane];

    float pq = __shfl_xor(xqn, 1);
    float pk = __shfl_xor(xkn, 1);
    float oq, ok;
    if (lane & 1) { oq = pq * sn + xqn * cs; ok = pk * sn + xkn * cs; }
    else          { oq = xqn * cs - pq * sn; ok = xkn * cs - pk * sn; }

    size_t o = (((size_t)b * N_HEADS + h) * NTOT + pos) * HEAD_DIM + lane;
    qO[o] = f2bf(oq * QSCALE);
    kO[o] = f2bf(ok);
    vO[o] = f2bf(xv);
  }
}

// ---------------------------------------------------------------------------
// V transpose: (BH, NTOT, 64) -> (BH, 64, NTOT), bf16, 64x64 tiles.
// ---------------------------------------------------------------------------
__global__ __launch_bounds__(256) void v_transpose(
    const unsigned short* __restrict__ v, unsigned short* __restrict__ vt)
{
  const int pt = blockIdx.x, bh = blockIdx.y;
  __shared__ unsigned short t[64][72];
  const int tid = threadIdx.x;
  const unsigned short* src = v + ((size_t)bh * NTOT + pt * 64) * 64;
#pragma unroll
  for (int c = 0; c < 2; ++c) {
    int off = c * 4096 + tid * 16;
    int row = off >> 7, c16 = (off & 127) >> 4;
    bf16x8 x = *(const bf16x8*)(src + row * 64 + c16 * 8);
#pragma unroll
    for (int j = 0; j < 8; ++j) t[row][c16 * 8 + j] = (unsigned short)x[j];
  }
  __syncthreads();
  unsigned short* dst = vt + (size_t)bh * 64 * NTOT + pt * 64;
#pragma unroll
  for (int c = 0; c < 2; ++c) {
    int off = c * 4096 + tid * 16;
    int d = off >> 7, p16 = (off & 127) >> 4;
    bf16x8 x;
#pragma unroll
    for (int j = 0; j < 8; ++j) x[j] = (short)t[p16 * 8 + j][d];
    *(bf16x8*)(dst + (size_t)d * NTOT + p16 * 8) = x;
  }
}

// ---------------------------------------------------------------------------
// MFMA flash attention, 32x32 fragments, in-register P, NO-MAX softmax.
// Bound: RMS-norm => ||q||=||k||=8, |S*log2e| <= 11.54 -> exp2 safe in fp32,
// so m-tracking/rescale are dropped entirely. P packed via v_perm (RTZ).
// S^T = mfma_32x32(K, Q): col(lane&31)=q -> l is lane-local.
// O^T = mfma_32x32(V^T, P). K/V dbuf + single barrier + setprio (r6-r9).
// ---------------------------------------------------------------------------
__global__ __launch_bounds__(256) void attn_mfma(
    const unsigned short* __restrict__ Qg, const unsigned short* __restrict__ Kg,
    const unsigned short* __restrict__ VTg,
    unsigned short* __restrict__ xb1, unsigned short* __restrict__ xb2)
{
  const int qt = blockIdx.x, bh = blockIdx.y;
  const int b = bh >> 4, head = bh & 15;
  const int tid = threadIdx.x, lane = tid & 63, w = tid >> 6;
  const int ql = lane & 31, hf = lane >> 5;

  __shared__ __align__(16) unsigned short Klds[2][64 * 64];   // 2 x 8 KB
  __shared__ __align__(16) unsigned short Vlds[2][64 * 64];   // 2 x 8 KB (V^T)

  const size_t base = (size_t)bh * NTOT * HEAD_DIM;

  // Q B-fragments: lane holds q = w*32 + ql, d = s*16 + hf*8 ..+7
  bf16x8 qf[4];
  {
    const unsigned short* qp =
        Qg + base + (size_t)(qt * 128 + w * 32 + ql) * 64 + hf * 8;
#pragma unroll
    for (int s = 0; s < 4; ++s) qf[s] = *(const bf16x8*)(qp + s * 16);
  }

  f32x16 acc_o[2];
#pragma unroll
  for (int dt = 0; dt < 2; ++dt)
#pragma unroll
    for (int r = 0; r < 16; ++r) acc_o[dt][r] = 0.0f;
  float l_run = 0.0f;

  const unsigned short* kp = Kg + base;
  const unsigned short* vtp = VTg + (size_t)bh * HEAD_DIM * NTOT;

#define STAGE(bf, kt)                                                         \
  {                                                                           \
    _Pragma("unroll")                                                         \
    for (int c = 0; c < 2; ++c) {                                             \
      int off = c * 4096 + tid * 16;                                          \
      int row = off >> 7;                                                     \
      int c16g = ((off & 127) >> 4) ^ (row & 7);                              \
      int dstb = c * 4096 + (tid >> 6) * 1024;                                \
      gload16(kp + (size_t)((kt) * 64 + row) * 64 + c16g * 8,                 \
              (char*)Klds[bf] + dstb);                                        \
      gload16(vtp + (size_t)row * NTOT + (kt) * 64 + c16g * 8,                \
              (char*)Vlds[bf] + dstb);                                        \
    }                                                                         \
  }

  STAGE(0, 0);

  for (int kt = 0; kt < NTOT / 64; ++kt) {
    const int cur = kt & 1;
    __syncthreads();   // rendezvous + vmcnt drain: buf[cur] staged,
                       // all waves done reading buf[cur^1]
    if (kt + 1 < NTOT / 64) STAGE(cur ^ 1, kt + 1);

    // S^T[t]: D[k32][q32], col = ql = q, row k = (r&3) + 8*(r>>2) + 4*hf
    f32x16 sacc[2];
#pragma unroll
    for (int t = 0; t < 2; ++t)
#pragma unroll
      for (int r = 0; r < 16; ++r) sacc[t][r] = 0.0f;
    __builtin_amdgcn_s_setprio(1);
#pragma unroll
    for (int t = 0; t < 2; ++t) {
#pragma unroll
      for (int s = 0; s < 4; ++s) {           // d contraction steps
        int row = t * 32 + ql;
        int colb = (s * 32 + hf * 16) ^ ((row & 7) << 4);
        bf16x8 kf = *(const bf16x8*)((const char*)Klds[cur] + row * 128 + colb);
        sacc[t] = __builtin_amdgcn_mfma_f32_32x32x16_bf16(
            kf, qf[s], sacc[t], 0, 0, 0);
      }
    }
    __builtin_amdgcn_s_setprio(0);

    // ---- no-max softmax: p = exp2(S'), straight-line, lane-local ----
    unsigned c0[8], c1[8];
    float rs = 0.0f;
    {
      float p0[16], p1[16];
#pragma unroll
      for (int r = 0; r < 16; ++r) {
        p0[r] = exp2f(sacc[0][r]);
        p1[r] = exp2f(sacc[1][r]);
        rs += p0[r] + p1[r];
      }
#pragma unroll
      for (int a = 0; a < 4; ++a) {
        c0[2 * a + 0] = packbf_rtz(p0[4 * a + 0], p0[4 * a + 1]);
        c0[2 * a + 1] = packbf_rtz(p0[4 * a + 2], p0[4 * a + 3]);
        c1[2 * a + 0] = packbf_rtz(p1[4 * a + 0], p1[4 * a + 1]);
        c1[2 * a + 1] = packbf_rtz(p1[4 * a + 2], p1[4 * a + 3]);
      }
    }
    rs += __shfl_xor(rs, 32);
    l_run += rs;

    // half-exchange: partner pairs via shfl_xor(32)
    unsigned r0[4], r1[4];
    r0[0] = __shfl_xor(hf ? c0[0] : c0[2], 32);
    r0[1] = __shfl_xor(hf ? c0[1] : c0[3], 32);
    r0[2] = __shfl_xor(hf ? c0[4] : c0[6], 32);
    r0[3] = __shfl_xor(hf ? c0[5] : c0[7], 32);
    r1[0] = __shfl_xor(hf ? c1[0] : c1[2], 32);
    r1[1] = __shfl_xor(hf ? c1[1] : c1[3], 32);
    r1[2] = __shfl_xor(hf ? c1[4] : c1[6], 32);
    r1[3] = __shfl_xor(hf ? c1[5] : c1[7], 32);

    // ---- PV: O^T[dt] += V^T-frag x P-frag over 4 k-steps ----
    __builtin_amdgcn_s_setprio(1);
#pragma unroll
    for (int s = 0; s < 4; ++s) {
      uint4 pw;
      const unsigned* cc = (s < 2) ? c0 : c1;
      const unsigned* rr = (s < 2) ? r0 : r1;
      if ((s & 1) == 0) {
        pw.x = hf ? rr[0] : cc[0];
        pw.y = hf ? rr[1] : cc[1];
        pw.z = hf ? cc[2] : rr[0];
        pw.w = hf ? cc[3] : rr[1];
      } else {
        pw.x = hf ? rr[2] : cc[4];
        pw.y = hf ? rr[3] : cc[5];
        pw.z = hf ? cc[6] : rr[2];
        pw.w = hf ? cc[7] : rr[3];
      }
      bf16x8 pfrag = __builtin_bit_cast(bf16x8, pw);
#pragma unroll
      for (int dt = 0; dt < 2; ++dt) {
        int row = dt * 32 + ql;
        int colb = (s * 32 + hf * 16) ^ ((row & 7) << 4);
        bf16x8 vf = *(const bf16x8*)((const char*)Vlds[cur] + row * 128 + colb);
        acc_o[dt] = __builtin_amdgcn_mfma_f32_32x32x16_bf16(
            vf, pfrag, acc_o[dt], 0, 0, 0);
      }
    }
    __builtin_amdgcn_s_setprio(0);
  }
#undef STAGE

  // epilogue: lane owns q = ql; d = dt*32 + 8*rq + 4*hf + b
  {
    float inv = 1.0f / l_run;
    int n = qt * 128 + w * 32 + ql;
    unsigned short* dst;
    if (n < SEQ1) dst = xb1 + ((size_t)b * SEQ1 + n) * D_MODEL;
    else          dst = xb2 + ((size_t)b * SEQ2 + (n - SEQ1)) * D_MODEL;
#pragma unroll
    for (int dt = 0; dt < 2; ++dt)
#pragma unroll
      for (int rq = 0; rq < 4; ++rq) {
        ushort4 o;
        o.x = f2bf(acc_o[dt][rq * 4 + 0] * inv);
        o.y = f2bf(acc_o[dt][rq * 4 + 1] * inv);
        o.z = f2bf(acc_o[dt][rq * 4 + 2] * inv);
        o.w = f2bf(acc_o[dt][rq * 4 + 3] * inv);
        *(ushort4*)(dst + head * 64 + dt * 32 + rq * 8 + hf * 4) = o;
      }
  }
}

// ---------------------------------------------------------------------------
extern "C" void kernel_launch(void* const* d_in, const int* in_sizes, int n_in,
                              void* d_out, int out_size, void* d_ws,
                              size_t ws_size, hipStream_t stream)
{
  (void)in_sizes; (void)n_in; (void)out_size; (void)ws_size;

  const float* x1  = (const float*)d_in[0];
  const float* x2  = (const float*)d_in[1];
  const float* Wq1 = (const float*)d_in[2];
  const float* bq1 = (const float*)d_in[3];
  const float* Wq2 = (const float*)d_in[4];
  const float* bq2 = (const float*)d_in[5];
  const float* Wo1 = (const float*)d_in[6];
  const float* bo1 = (const float*)d_in[7];
  const float* Wo2 = (const float*)d_in[8];
  const float* bo2 = (const float*)d_in[9];
  const float* qs1 = (const float*)d_in[10];
  const float* ks1 = (const float*)d_in[11];
  const float* qs2 = (const float*)d_in[12];
  const float* ks2 = (const float*)d_in[13];
  float* out = (float*)d_out;

  unsigned short* ws = (unsigned short*)d_ws;
  const size_t SX1 = (size_t)BATCH * SEQ1 * D_MODEL;
  const size_t SX2 = (size_t)BATCH * SEQ2 * D_MODEL;
  const size_t SW  = (size_t)3 * D_MODEL * D_MODEL;
  const size_t SWO = (size_t)D_MODEL * D_MODEL;
  const size_t SQ1 = (size_t)BATCH * SEQ1 * 3 * D_MODEL;
  const size_t SQ2 = (size_t)BATCH * SEQ2 * 3 * D_MODEL;
  const size_t SH  = (size_t)BATCH * N_HEADS * NTOT * HEAD_DIM;

  unsigned short* x1b  = ws;
  unsigned short* x2b  = x1b + SX1;
  unsigned short* Wq1b = x2b + SX2;
  unsigned short* Wq2b = Wq1b + SW;
  unsigned short* Wo1b = Wq2b + SW;
  unsigned short* Wo2b = Wo1b + SWO;
  unsigned short* qkv1 = Wo2b + SWO;
  unsigned short* qkv2 = qkv1 + SQ1;
  unsigned short* qb   = qkv2 + SQ2;
  unsigned short* kb   = qb + SH;
  unsigned short* vb   = kb + SH;
  unsigned short* vtb  = vb + SH;
  unsigned short* xb1  = vtb + SH;          // (B,SEQ1,1024) bf16
  unsigned short* xb2  = xb1 + SX1;         // (B,SEQ2,1024) bf16

  // fused fp32 -> bf16 conversion
  CvtArgs ca;
  ca.src[0] = x1;  ca.dst[0] = x1b;
  ca.src[1] = x2;  ca.dst[1] = x2b;
  ca.src[2] = Wq1; ca.dst[2] = Wq1b;
  ca.src[3] = Wq2; ca.dst[3] = Wq2b;
  ca.src[4] = Wo1; ca.dst[4] = Wo1b;
  ca.src[5] = Wo2; ca.dst[5] = Wo2b;
  ca.prefix[0] = 0;
  ca.prefix[1] = (int)SX1;
  ca.prefix[2] = (int)(SX1 + SX2);
  ca.prefix[3] = (int)(SX1 + SX2 + SW);
  ca.prefix[4] = (int)(SX1 + SX2 + 2 * SW);
  ca.prefix[5] = (int)(SX1 + SX2 + 2 * SW + SWO);
  ca.prefix[6] = (int)(SX1 + SX2 + 2 * SW + 2 * SWO);
  cvt_all<<<(ca.prefix[6] / 4 + 255) / 256, 256, 0, stream>>>(ca);

  // QKV projections: one batched dispatch (bf16 out)
  {
    GemmSeg s0{x1b, Wq1b, bq1, qkv1, 3 * D_MODEL, D_MODEL, 3 * D_MODEL / 128};
    GemmSeg s1{x2b, Wq2b, bq2, qkv2, 3 * D_MODEL, D_MODEL, 3 * D_MODEL / 128};
    int t0 = (BATCH * SEQ1 / 128) * (3 * D_MODEL / 128);   // 576
    int t1 = (BATCH * SEQ2 / 128) * (3 * D_MODEL / 128);   // 192
    gemm2<1><<<t0 + t1, 256, 0, stream>>>(s0, s1, t0);
  }

  // RMSNorm + RoPE + scatter
  qkv_transform<<<BATCH * (SEQ1 + SEQ2), 256, 0, stream>>>(
      qkv1, qkv2, qs1, ks1, qs2, ks2, qb, kb, vb);

  // V transpose for PV operand
  v_transpose<<<dim3(NTOT / 64, BATCH * N_HEADS), 256, 0, stream>>>(vb, vtb);

  // attention (QBLK=128, 4 waves x 32q, 32x32 MFMA, in-register P, no-max)
  attn_mfma<<<dim3(NTOT / 128, BATCH * N_HEADS), 256, 0, stream>>>(
      qb, kb, vtb, xb1, xb2);

  // output projections: one batched dispatch (f32 out)
  {
    GemmSeg s0{xb1, Wo1b, bo1, out, D_MODEL, D_MODEL, D_MODEL / 128};
    GemmSeg s1{xb2, Wo2b, bo2, out + (size_t)BATCH * SEQ1 * D_MODEL,
               D_MODEL, D_MODEL, D_MODEL / 128};
    int t0 = (BATCH * SEQ1 / 128) * (D_MODEL / 128);   // 192
    int t1 = (BATCH * SEQ2 / 128) * (D_MODEL / 128);   // 64
    gemm2<0><<<t0 + t1, 256, 0, stream>>>(s0, s1, t0);
  }
}